// Round 11
// baseline (68.830 us; speedup 1.0000x reference)
//
#include <hip/hip_runtime.h>
#include <hip/hip_bf16.h>

// InfoNCE loss, B=8192, D=128, T=0.1.
// sim = normalize(E) @ normalize(E)^T / T; per-row masked exp-sums; scalar loss.
// Diagonal included in fused sums, subtracted in finalize via prep-computed
// diag[i] = exp2(dot_ii) with identical rounding to sim's operands.
//
// R11: label-sorted j-side. 100 classes -> ~63% of 32-row j-tiles are
// class-PURE: pos needs ONE cmp/sel per tile (not per element) and the
// epilogue chain collapses to exp2 + pairwise tree-sum. Straddle tiles keep
// the R5 per-element path. Deterministic counting sort (1 block, no atomics);
// sim stages j-rows via perm[] gather (global_load_lds src is per-lane, m173).
// i-side / diag / fin unchanged; occupancy experiments abandoned (R4-R10:
// caps spill, low-VGPR shapes don't help -> sim is latency-bound in the
// epilogue chains, not occupancy-bound).
//
// ws layout:
//   pos_part f32[32][8192]  1MB   (sim)
//   all_part f32[32][8192]  1MB   (sim)
//   lab32    i32[8192]            (prep)
//   diag     f32[8192]            (prep)
//   perm     u32[8192]            (sort; sorted pos -> natural row)
//   slab8p   u8[8192]             (sort; sorted labels, 32-group permuted)
//   meta     u16[256]             (sort; per-32-tile class or 0xFFFF)
//   fin_s    f32[32], fin_c f32[32], ticket u32 (fin; ticket zeroed by prep)
//   Ebf      bf16[8192*128] 2MB   (prep; unit rows, j-side / LDS)
//   Ebf2     bf16[8192*128] 2MB   (prep; K_SCALE-scaled rows, i-side regs)

#define B_ROWS 8192
#define D_DIM 128
#define NCLS 100
#define K_SCALE 14.426950408889634f  // log2(e)/0.1
#define JSPLIT 32
#define JCHUNK (B_ROWS / JSPLIT)  // 256
#define TILE_J 64
#define NT (JCHUNK / TILE_J)  // 4
#define BM 256                // i-rows per block = 4 waves x 64

typedef __attribute__((ext_vector_type(8))) short bf16x8;
typedef __attribute__((ext_vector_type(16))) float f32x16;
typedef __attribute__((ext_vector_type(4))) unsigned int u32x4;
typedef unsigned short u16;
typedef unsigned int u32;
typedef unsigned long long u64;

static __device__ __forceinline__ unsigned short bf16_bits(float x) {
  __hip_bfloat16 h = __float2bfloat16(x);
  unsigned short u;
  __builtin_memcpy(&u, &h, 2);
  return u;
}
static __device__ __forceinline__ float f32_from_bits(u32 b) {
  float f;
  __builtin_memcpy(&f, &b, 4);
  return f;
}
static __device__ __forceinline__ float bf16f(unsigned short u) {
  return f32_from_bits((u32)u << 16);
}

// Normalize rows in fp32; emit unit bf16 matrix (j-side), scaled bf16 matrix
// (i-side), labels i32, diag; zero the fin ticket.
__global__ __launch_bounds__(256) void prep_kernel(
    const float* __restrict__ E, const long long* __restrict__ labels,
    __hip_bfloat16* __restrict__ Ebf, __hip_bfloat16* __restrict__ Ebf2,
    int* __restrict__ lab32, float* __restrict__ diag,
    u32* __restrict__ ticket) {
  if (blockIdx.x == 0 && threadIdx.x == 0) *ticket = 0u;
  const int wid = threadIdx.x >> 6, lane = threadIdx.x & 63;
  const int row = blockIdx.x * 4 + wid;
  const float2 v = *(const float2*)(E + (u64)row * D_DIM + lane * 2);
  float ss = v.x * v.x + v.y * v.y;
#pragma unroll
  for (int m = 1; m < 64; m <<= 1) ss += __shfl_xor(ss, m);
  const float scale = 1.0f / fmaxf(sqrtf(ss), 1e-12f);
  const unsigned short bx = bf16_bits(v.x * scale);
  const unsigned short by = bf16_bits(v.y * scale);
  ((u32*)Ebf)[(u64)row * (D_DIM / 2) + lane] = ((u32)by << 16) | bx;
  const float fx = bf16f(bx), fy = bf16f(by);
  const unsigned short axb = bf16_bits(fx * K_SCALE);
  const unsigned short ayb = bf16_bits(fy * K_SCALE);
  ((u32*)Ebf2)[(u64)row * (D_DIM / 2) + lane] = ((u32)ayb << 16) | axb;
  float dot = bf16f(axb) * fx + bf16f(ayb) * fy;
#pragma unroll
  for (int m = 1; m < 64; m <<= 1) dot += __shfl_xor(dot, m);
  if (lane == 0) diag[row] = __builtin_amdgcn_exp2f(dot);

  const int gtid = blockIdx.x * 256 + threadIdx.x;
  if (gtid < B_ROWS) lab32[gtid] = (int)labels[gtid];
}

// Deterministic counting sort by label. 1 block, 256 threads; thread t owns
// rows [t*32, t*32+32). Per-chunk histograms (no atomics) -> class-major scan
// -> ordered placement. Emits perm, permuted sorted label bytes, per-tile meta.
__global__ __launch_bounds__(256) void sort_kernel(
    const int* __restrict__ lab32, u32* __restrict__ perm,
    unsigned char* __restrict__ slab8p, u16* __restrict__ meta) {
  __shared__ u16 chist[256][NCLS];      // 51.2KB
  __shared__ unsigned char slab[B_ROWS];  // 8KB
  __shared__ u32 cbase[NCLS];
  __shared__ u32 tot[NCLS];
  const int t = threadIdx.x;

#pragma unroll 4
  for (int c = 0; c < NCLS; ++c) chist[t][c] = 0;
  __syncthreads();
  int mylab[32];
#pragma unroll
  for (int k = 0; k < 32; ++k) {
    mylab[k] = lab32[t * 32 + k];
    chist[t][mylab[k]]++;
  }
  __syncthreads();
  if (t < NCLS) {  // exclusive scan over chunks within class t
    u32 run = 0;
    for (int ch = 0; ch < 256; ++ch) {
      const u16 v = chist[ch][t];
      chist[ch][t] = (u16)run;
      run += v;
    }
    tot[t] = run;
  }
  __syncthreads();
  if (t == 0) {  // exclusive scan over classes
    u32 run = 0;
    for (int c = 0; c < NCLS; ++c) {
      cbase[c] = run;
      run += tot[c];
    }
  }
  __syncthreads();
#pragma unroll
  for (int k = 0; k < 32; ++k) {  // ordered placement (deterministic)
    const int c = mylab[k];
    const u32 pos = cbase[c] + (u32)(chist[t][c]++);
    perm[pos] = (u32)(t * 32 + k);
    slab[pos] = (unsigned char)c;
  }
  __syncthreads();
#pragma unroll
  for (int k = 0; k < 32; ++k) {  // permuted label bytes (R5 32-group layout)
    const int pos = t * 32 + k;
    const int local = pos & 31;
    const int h = (local >> 2) & 1;
    const int rr = (local & 3) + 4 * (local >> 3);
    slab8p[(pos & ~31) + h * 16 + rr] = slab[pos];
  }
  // per-32-row-tile meta: class byte if pure, 0xFFFF if straddle
  const unsigned char a = slab[t * 32], b = slab[t * 32 + 31];
  meta[t] = (a == b) ? (u16)a : (u16)0xFFFF;
}

// Fused sim + exp + masked row partial sums (R5 structure, sorted j).
// 4 waves; wave w owns 64 i-rows (2 pinned ifrag sets) at bx*256+w*64.
// 32x32x16 MFMA, swapped operands D[j][i] = mfma(jfrag_lds, ifrag_reg):
// i = lane&31, j(reg r, hi) = (r&3)+8*(r>>2)+4*hi  [j in SORTED index space].
// Pure j-tile (meta<0x100): pos = (labi==class) ? tile_sum : 0 -- 1 sel/tile.
// grid = (32, JSPLIT); per-js partial sums written non-atomically.
__global__ __launch_bounds__(256) void sim_kernel(
    const __hip_bfloat16* __restrict__ Ebf,
    const __hip_bfloat16* __restrict__ Ebf2, const int* __restrict__ lab32,
    const u32* __restrict__ perm, const unsigned char* __restrict__ slab8p,
    const u16* __restrict__ meta, float* __restrict__ pos_part,
    float* __restrict__ all_part) {
  __shared__ __align__(16) unsigned char lds[2][TILE_J * 256];

  const int t = threadIdx.x;
  const int wid = t >> 6, lane = t & 63;
  const int l31 = lane & 31, hi = lane >> 5;
  const int i0w = blockIdx.x * BM + wid * 64;
  const int jbase0 = blockIdx.y * JCHUNK;

  // two register-resident i-side fragment sets (pre-scaled in prep), pinned.
  bf16x8 ifragA[8], ifragB[8];
  {
    const __hip_bfloat16* srcA = Ebf2 + (u64)(i0w + l31) * D_DIM + hi * 8;
    const __hip_bfloat16* srcB = srcA + 32 * D_DIM;
#pragma unroll
    for (int ks = 0; ks < 8; ++ks) {
      ifragA[ks] = *(const bf16x8*)(srcA + ks * 16);
      ifragB[ks] = *(const bf16x8*)(srcB + ks * 16);
      asm volatile("" : "+v"(ifragA[ks]));
      asm volatile("" : "+v"(ifragB[ks]));
    }
  }
  const int labiA = lab32[i0w + l31];
  const int labiB = lab32[i0w + 32 + l31];

  // swizzled LDS read addressing (R5): offset = l31*256 + ((slot^key)<<4)
  const u32 key = lane & 15;
  const u32 M = (key & 14) << 4;
  const u32 base2 = (u32)(l31 * 256) + (((hi ^ (key & 1)) & 1) << 4);

  // staging via perm gather (m173: global src per-lane, LDS dest linear)
  const unsigned char* gb = (const unsigned char*)Ebf;
  const int l4 = lane >> 4, sl = lane & 15;
  const u32 sx4 = (u32)(sl ^ l4) << 4;

  auto stage = [&](int buf, int tile) {
#pragma unroll
    for (int i = 0; i < 4; ++i) {
      const int jrow = jbase0 + tile * TILE_J + wid * 16 + i * 4 + l4;
      const u32 srow = perm[jrow];
      const u32 goff = srow * 256u + (sx4 ^ (u32)(i << 6));
      __builtin_amdgcn_global_load_lds(
          (const __attribute__((address_space(1))) u32*)(gb + goff),
          (__attribute__((address_space(3)))
               u32*)(&lds[buf][wid * 4096 + i * 1024]),
          16, 0, 0);
    }
  };

  float posA = 0.f, posB = 0.f, allA = 0.f, allB = 0.f;

  stage(0, 0);
  __syncthreads();

  for (int tile = 0; tile < NT; ++tile) {
    const int cur = tile & 1;
    if (tile + 1 < NT) stage(cur ^ 1, tile + 1);
    const int jbase = jbase0 + tile * TILE_J;
    const unsigned char* lbuf = lds[cur];
#pragma unroll
    for (int jsub = 0; jsub < 2; ++jsub) {
      f32x16 acc0 = {}, acc1 = {};
#pragma unroll
      for (int ks = 0; ks < 8; ++ks) {
        bf16x8 jfrag = *(const bf16x8*)(lbuf + base2 +
                                        (((u32)(ks << 5)) ^ M) + jsub * 8192);
        acc0 = __builtin_amdgcn_mfma_f32_32x32x16_bf16(jfrag, ifragA[ks], acc0,
                                                       0, 0, 0);
        acc1 = __builtin_amdgcn_mfma_f32_32x32x16_bf16(jfrag, ifragB[ks], acc1,
                                                       0, 0, 0);
      }
      const int mt = (int)meta[(jbase >> 5) + jsub];
      if (mt != 0xFFFF) {
        // PURE tile: tree-sum of exps; one cmp/sel per i-row accumulator.
        float pa[16], pb[16];
#pragma unroll
        for (int r = 0; r < 16; ++r) {
          pa[r] = __builtin_amdgcn_exp2f(acc0[r]);
          pb[r] = __builtin_amdgcn_exp2f(acc1[r]);
        }
#pragma unroll
        for (int m = 8; m >= 1; m >>= 1) {
#pragma unroll
          for (int r = 0; r < m; ++r) {
            pa[r] += pa[r + m];
            pb[r] += pb[r + m];
          }
        }
        allA += pa[0];
        allB += pb[0];
        posA += (labiA == mt) ? pa[0] : 0.f;
        posB += (labiB == mt) ? pb[0] : 0.f;
      } else {
        // STRADDLE tile: per-element label path (R5).
        const u32x4 labv =
            *(const u32x4*)(slab8p + jbase + jsub * 32 + hi * 16);
#pragma unroll
        for (int r = 0; r < 16; ++r) {
          const int labj = (int)((labv[r >> 2] >> ((r & 3) * 8)) & 0xff);
          const float p0 = __builtin_amdgcn_exp2f(acc0[r]);
          const float p1 = __builtin_amdgcn_exp2f(acc1[r]);
          allA += p0;
          allB += p1;
          posA += (labj == labiA) ? p0 : 0.f;
          posB += (labj == labiB) ? p1 : 0.f;
        }
      }
    }
    __syncthreads();
  }

  // lanes l and l+32 hold same i, disjoint j-quarters
  posA += __shfl_xor(posA, 32);
  allA += __shfl_xor(allA, 32);
  posB += __shfl_xor(posB, 32);
  allB += __shfl_xor(allB, 32);
  if (hi == 0) {
    const u64 off = (u64)blockIdx.y * B_ROWS;
    pos_part[off + i0w + l31] = posA;
    all_part[off + i0w + l31] = allA;
    pos_part[off + i0w + 32 + l31] = posB;
    all_part[off + i0w + 32 + l31] = allB;
  }
}

// Single finalize: 32 blocks reduce their 256 rows; last block (ticket)
// combines the 32 partials in fixed order -> deterministic.
__global__ __launch_bounds__(256) void fin_kernel(
    const float* __restrict__ pos_part, const float* __restrict__ all_part,
    const float* __restrict__ diag, float* __restrict__ fin_s,
    float* __restrict__ fin_c, u32* __restrict__ ticket,
    float* __restrict__ out) {
  const int row = blockIdx.x * 256 + threadIdx.x;
  float ps = 0.f, as_ = 0.f;
#pragma unroll 8
  for (int js = 0; js < JSPLIT; ++js) {
    ps += pos_part[(u64)js * B_ROWS + row];
    as_ += all_part[(u64)js * B_ROWS + row];
  }
  const float d = diag[row];
  ps -= d;
  as_ -= d;
  float s = 0.f, c = 0.f;
  if (ps > 0.f) {
    s = logf(as_) - logf(ps);
    c = 1.f;
  }
#pragma unroll
  for (int m = 1; m < 64; m <<= 1) {
    s += __shfl_xor(s, m);
    c += __shfl_xor(c, m);
  }
  __shared__ float ls[4], lc[4];
  const int wid = threadIdx.x >> 6, lane = threadIdx.x & 63;
  if (lane == 0) {
    ls[wid] = s;
    lc[wid] = c;
  }
  __syncthreads();
  if (threadIdx.x == 0) {
    __hip_atomic_store(&fin_s[blockIdx.x], ls[0] + ls[1] + ls[2] + ls[3],
                       __ATOMIC_RELEASE, __HIP_MEMORY_SCOPE_AGENT);
    __hip_atomic_store(&fin_c[blockIdx.x], lc[0] + lc[1] + lc[2] + lc[3],
                       __ATOMIC_RELEASE, __HIP_MEMORY_SCOPE_AGENT);
    const u32 tk = __hip_atomic_fetch_add(ticket, 1u, __ATOMIC_ACQ_REL,
                                          __HIP_MEMORY_SCOPE_AGENT);
    if (tk == 31u) {  // last block: fixed-order combine
      float ts = 0.f, tc = 0.f;
      for (int b = 0; b < 32; ++b) {
        ts += __hip_atomic_load(&fin_s[b], __ATOMIC_ACQUIRE,
                                __HIP_MEMORY_SCOPE_AGENT);
        tc += __hip_atomic_load(&fin_c[b], __ATOMIC_ACQUIRE,
                                __HIP_MEMORY_SCOPE_AGENT);
      }
      out[0] = ts / fmaxf(tc, 1.0f);
    }
  }
}

extern "C" void kernel_launch(void* const* d_in, const int* in_sizes, int n_in,
                              void* d_out, int out_size, void* d_ws,
                              size_t ws_size, hipStream_t stream) {
  const float* E = (const float*)d_in[0];
  const long long* labels = (const long long*)d_in[1];

  float* pos_part = (float*)d_ws;                          // 32*8192
  float* all_part = pos_part + JSPLIT * B_ROWS;            // 32*8192
  int* lab32 = (int*)(all_part + JSPLIT * B_ROWS);         // 8192
  float* diag = (float*)(lab32 + B_ROWS);                  // 8192
  u32* perm = (u32*)(diag + B_ROWS);                       // 8192
  unsigned char* slab8p = (unsigned char*)(perm + B_ROWS); // 8192
  u16* meta = (u16*)(slab8p + B_ROWS);                     // 256
  float* fin_s = (float*)(meta + 256);                     // 32
  float* fin_c = fin_s + 32;                               // 32
  u32* ticket = (u32*)(fin_c + 32);                        // 1 (+pad)
  __hip_bfloat16* Ebf = (__hip_bfloat16*)(ticket + 4);
  __hip_bfloat16* Ebf2 = Ebf + (u64)B_ROWS * D_DIM;

  prep_kernel<<<B_ROWS / 4, 256, 0, stream>>>(E, labels, Ebf, Ebf2, lab32,
                                              diag, ticket);
  sort_kernel<<<1, 256, 0, stream>>>(lab32, perm, slab8p, meta);
  sim_kernel<<<dim3(B_ROWS / BM, JSPLIT), 256, 0, stream>>>(
      Ebf, Ebf2, lab32, perm, slab8p, meta, pos_part, all_part);
  fin_kernel<<<B_ROWS / 256, 256, 0, stream>>>(pos_part, all_part, diag,
                                               fin_s, fin_c, ticket,
                                               (float*)d_out);
}